// Round 2
// baseline (57330.420 us; speedup 1.0000x reference)
//
#include <hip/hip_runtime.h>
#include <math.h>

// Problem constants (fixed by setup_inputs)
#define V_   2
#define B_   8
#define S_   2048
#define D_   512
#define VOCAB_ 8192
#define STEPS_ 16
#define DECAY_ 0.999f
#define EPS_ 1e-6f
#define VB_  (V_ * B_)       // 16
#define R_   (VB_ * S_)      // 32768 token rows
#define RD_  ((long)R_ * D_) // 16777216 floats

typedef unsigned int u32;
typedef unsigned short u16;
typedef __attribute__((ext_vector_type(8)))  short bf16x8;   // MFMA A/B frag (4 VGPR)
typedef __attribute__((ext_vector_type(16))) float f32x16;   // MFMA C/D frag (16 VGPR)

enum Act { ACT_IDENT = 0, ACT_SIGMOID = 1, ACT_GELU = 2, ACT_PHI = 3 };

template <int ACT>
__device__ __forceinline__ float act_fn(float x) {
    if (ACT == ACT_SIGMOID) return 1.0f / (1.0f + __expf(-x));
    if (ACT == ACT_GELU)    return 0.5f * x * (1.0f + erff(x * 0.70710678118654752f));
    if (ACT == ACT_PHI)     return x > 0.0f ? x + 1.0f : __expf(x);  // elu(x)+1
    return x;
}

// Exact 3-way bf16 split (truncation): x == hi + mid + lo bit-exactly in fp32.
__device__ __forceinline__ void split3(float x, u32& h, u32& m, u32& l) {
    u32 bx = __float_as_uint(x);
    u32 hb = bx & 0xFFFF0000u;
    float r = x - __uint_as_float(hb);
    u32 rb = __float_as_uint(r);
    u32 mb = rb & 0xFFFF0000u;
    float r2 = r - __uint_as_float(mb);
    h = hb >> 16;
    m = mb >> 16;
    l = __float_as_uint(r2) >> 16;
}

// ---------------------------------------------------------------------------
// Plane GEMM: A = activation planes [M][K] bf16 ×3 (plane stride sAp),
//             B = pre-transposed weight planes [N][K] bf16 ×3 (stride sBp).
// C = beta*C + Gate? ⊙ (alpha * act(A·B)), optional split-plane output.
// 128×128 tile, BK=32, 256 thr = 4 waves × 64×64, 6 plane products
// (HH,HM,MH,MM,HL,LH — dropped ML/LM ~2^-24 rel). No split VALU in loop.
// LDS 48KB: A planes [0,12288) u16, B planes [12288,24576); chunk-XOR swizzle.
// ---------------------------------------------------------------------------
template <int ACT, bool HAS_GATE, bool WRITE_C, bool WRITE_PLANES>
__launch_bounds__(256)
__global__ void gemm_pl(const u16* __restrict__ Ap, const u16* __restrict__ Bp,
                        float* __restrict__ C, const float* __restrict__ Gate,
                        u16* __restrict__ Pout,
                        int M, int N, int K,
                        long sAp, long sBp, long sPout,
                        float alpha, float beta) {
    __shared__ u16 lds[24576];
    const int colBase = blockIdx.x * 128;
    const int rowBase = blockIdx.y * 128;
    const int t    = threadIdx.x;
    const int lane = t & 63;
    const int w    = t >> 6;
    const int wm   = (w >> 1) * 64;
    const int wn   = (w & 1) * 64;
    const int l31  = lane & 31;
    const int lg   = lane >> 5;

    // staging map: 12 × 16B chunks per thread (i<6 → A, else B)
    u32 goff[12];
    int doff[12];
#pragma unroll
    for (int i = 0; i < 12; i++) {
        const int id  = i * 256 + t;
        const int op  = id / 1536;
        const int rem = id - op * 1536;
        const int pid = rem >> 9;
        const int rid = rem & 511;
        const int row = rid >> 2, c = rid & 3;
        const int sx  = (row & 3) ^ ((row >> 2) & 3);
        if (op == 0) goff[i] = (u32)((long)pid * sAp + (long)(rowBase + row) * K + c * 8);
        else         goff[i] = (u32)((long)pid * sBp + (long)(colBase + row) * K + c * 8);
        doff[i] = op * 12288 + pid * 4096 + row * 32 + ((c ^ sx) << 3);
    }

    f32x16 acc[2][2];
#pragma unroll
    for (int a = 0; a < 2; a++)
#pragma unroll
        for (int b = 0; b < 2; b++)
#pragma unroll
            for (int r = 0; r < 16; r++) acc[a][b][r] = 0.0f;

    uint4 st[12];
#pragma unroll
    for (int i = 0; i < 12; i++)
        st[i] = *(const uint4*)((i < 6 ? Ap : Bp) + goff[i]);

    for (int k0 = 0; k0 < K; k0 += 32) {
        __syncthreads();  // prior tile's frag reads complete
#pragma unroll
        for (int i = 0; i < 12; i++) *(uint4*)&lds[doff[i]] = st[i];
        __syncthreads();
        if (k0 + 32 < K) {
#pragma unroll
            for (int i = 0; i < 12; i++)
                st[i] = *(const uint4*)((i < 6 ? Ap : Bp) + goff[i] + (k0 + 32));
        }

        bf16x8 af[2][2][3];  // [at][kh][plane]
#pragma unroll
        for (int at = 0; at < 2; at++) {
            const int m  = wm + at * 32 + l31;
            const int sx = (m & 3) ^ ((m >> 2) & 3);
#pragma unroll
            for (int kh = 0; kh < 2; kh++) {
                const int ck = kh * 2 + lg;
#pragma unroll
                for (int p = 0; p < 3; p++)
                    af[at][kh][p] = *(const bf16x8*)&lds[p * 4096 + m * 32 + (((ck ^ sx) & 3) << 3)];
            }
        }
#pragma unroll
        for (int bt = 0; bt < 2; bt++) {
            const int n  = wn + bt * 32 + l31;
            const int sx = (n & 3) ^ ((n >> 2) & 3);
            bf16x8 bf[2][3];
#pragma unroll
            for (int kh = 0; kh < 2; kh++) {
                const int ck = kh * 2 + lg;
#pragma unroll
                for (int p = 0; p < 3; p++)
                    bf[kh][p] = *(const bf16x8*)&lds[12288 + p * 4096 + n * 32 + (((ck ^ sx) & 3) << 3)];
            }
#define DO_PROD(pa, pb)                                                        \
    _Pragma("unroll")                                                          \
    for (int at = 0; at < 2; at++)                                             \
        _Pragma("unroll")                                                      \
        for (int kh = 0; kh < 2; kh++)                                         \
            acc[at][bt] = __builtin_amdgcn_mfma_f32_32x32x16_bf16(             \
                af[at][kh][pa], bf[kh][pb], acc[at][bt], 0, 0, 0);
            DO_PROD(0, 0) DO_PROD(0, 1) DO_PROD(1, 0) DO_PROD(1, 1)
            DO_PROD(0, 2) DO_PROD(2, 0)
#undef DO_PROD
        }
    }

    // epilogue. C/D layout: col=lane&31, row=(r&3)+8*(r>>2)+4*(lane>>5)
#pragma unroll
    for (int at = 0; at < 2; at++)
#pragma unroll
        for (int bt = 0; bt < 2; bt++) {
            const long gc = colBase + wn + bt * 32 + l31;
#pragma unroll
            for (int r = 0; r < 16; r++) {
                const long gr = rowBase + wm + at * 32 + (r & 3) + 8 * (r >> 2) + 4 * lg;
                const long idx = gr * (long)N + gc;
                float vx = alpha * act_fn<ACT>(acc[at][bt][r]);
                if (HAS_GATE) vx *= Gate[idx];
                if (WRITE_C) {
                    if (beta != 0.0f) vx += beta * C[idx];
                    C[idx] = vx;
                }
                if (WRITE_PLANES) {
                    u32 hh, mm, ll; split3(vx, hh, mm, ll);
                    Pout[idx] = (u16)hh;
                    Pout[sPout + idx] = (u16)mm;
                    Pout[2 * sPout + idx] = (u16)ll;
                }
            }
        }
}

// ---------------------------------------------------------------------------
// fp32-input split GEMM (for acc/mixed where inputs must stay fp32).
// In-kernel split3, 6 products. Optional plane output (mixed → Wo fast path).
// ---------------------------------------------------------------------------
template <bool TRANS_A>
__device__ __forceinline__ void load_tile(const float* __restrict__ A,
                                          const float* __restrict__ Bm,
                                          int M, int N, int K,
                                          int rowBase, int colBase, int k0, int t,
                                          float4 (&av)[4], float4 (&bv)[4]) {
    if (!TRANS_A) {
#pragma unroll
        for (int i = 0; i < 4; i++) {
            const int id = i * 256 + t;
            const int m = id >> 3, kq = id & 7;
            av[i] = *(const float4*)&A[(long)(rowBase + m) * K + k0 + kq * 4];
        }
    } else {
#pragma unroll
        for (int i = 0; i < 4; i++) {
            const int id = i * 256 + t;
            const int kq = id >> 7, m = id & 127;
            const float* p0 = &A[(long)(k0 + kq * 4) * M + rowBase + m];
            av[i].x = p0[0]; av[i].y = p0[M]; av[i].z = p0[2 * M]; av[i].w = p0[3 * M];
        }
    }
#pragma unroll
    for (int i = 0; i < 4; i++) {
        const int id = i * 256 + t;
        const int kq = id >> 7, n = id & 127;
        const float* p0 = &Bm[(long)(k0 + kq * 4) * N + colBase + n];
        bv[i].x = p0[0]; bv[i].y = p0[N]; bv[i].z = p0[2 * N]; bv[i].w = p0[3 * N];
    }
}

__device__ __forceinline__ void stage_quad(u32* base, int row, int kq, float4 v) {
    u32 h0, m0, l0, h1, m1, l1, h2, m2, l2, h3, m3, l3;
    split3(v.x, h0, m0, l0); split3(v.y, h1, m1, l1);
    split3(v.z, h2, m2, l2); split3(v.w, h3, m3, l3);
    const int sw = ((kq >> 1) ^ (row & 3) ^ ((row >> 2) & 3));
    u32* p = base + row * 16 + sw * 4 + (kq & 1) * 2;
    p[0]    = h0 | (h1 << 16); p[1]    = h2 | (h3 << 16);
    p[2048] = m0 | (m1 << 16); p[2049] = m2 | (m3 << 16);
    p[4096] = l0 | (l1 << 16); p[4097] = l2 | (l3 << 16);
}

template <int ACT, bool HAS_GATE, bool TRANS_A, bool WRITE_C, bool WRITE_PLANES>
__launch_bounds__(256)
__global__ void gemm_mfma(const float* __restrict__ A, const float* __restrict__ Bm,
                          float* __restrict__ C, const float* __restrict__ Gate,
                          u16* __restrict__ Pout,
                          int M, int N, int K,
                          long sA, long sB, long sC, long sPout,
                          float alpha, float beta) {
    __shared__ u32 lds[12288];
    const int bz = blockIdx.z;
    A  += (long)bz * sA;
    Bm += (long)bz * sB;
    if (WRITE_C)      C    += (long)bz * sC;
    if (WRITE_PLANES) Pout += (long)bz * sC;
    const int colBase = blockIdx.x * 128;
    const int rowBase = blockIdx.y * 128;
    const int t    = threadIdx.x;
    const int lane = t & 63;
    const int w    = t >> 6;
    const int wm   = (w >> 1) * 64;
    const int wn   = (w & 1) * 64;
    const int l31  = lane & 31;
    const int lg   = lane >> 5;

    f32x16 acc[2][2];
#pragma unroll
    for (int a = 0; a < 2; a++)
#pragma unroll
        for (int b = 0; b < 2; b++)
#pragma unroll
            for (int r = 0; r < 16; r++) acc[a][b][r] = 0.0f;

    float4 av[4], bv[4];
    load_tile<TRANS_A>(A, Bm, M, N, K, rowBase, colBase, 0, t, av, bv);

    for (int k0 = 0; k0 < K; k0 += 32) {
        __syncthreads();
#pragma unroll
        for (int i = 0; i < 4; i++) {
            const int id = i * 256 + t;
            int row, kq;
            if (!TRANS_A) { row = id >> 3; kq = id & 7; }
            else          { kq = id >> 7; row = id & 127; }
            stage_quad(lds, row, kq, av[i]);
        }
#pragma unroll
        for (int i = 0; i < 4; i++) {
            const int id = i * 256 + t;
            const int kq = id >> 7, n = id & 127;
            stage_quad(lds + 6144, n, kq, bv[i]);
        }
        __syncthreads();

        if (k0 + 32 < K)
            load_tile<TRANS_A>(A, Bm, M, N, K, rowBase, colBase, k0 + 32, t, av, bv);

        bf16x8 af[2][2][3];
#pragma unroll
        for (int at = 0; at < 2; at++) {
            const int m  = wm + at * 32 + l31;
            const int sx = (m & 3) ^ ((m >> 2) & 3);
#pragma unroll
            for (int kh = 0; kh < 2; kh++) {
                const int c = kh * 2 + lg;
#pragma unroll
                for (int p = 0; p < 3; p++)
                    af[at][kh][p] = *(const bf16x8*)&lds[p * 2048 + m * 16 + (((c ^ sx) & 3) << 2)];
            }
        }
#pragma unroll
        for (int bt = 0; bt < 2; bt++) {
            const int n  = wn + bt * 32 + l31;
            const int sx = (n & 3) ^ ((n >> 2) & 3);
            bf16x8 bf[2][3];
#pragma unroll
            for (int kh = 0; kh < 2; kh++) {
                const int c = kh * 2 + lg;
#pragma unroll
                for (int p = 0; p < 3; p++)
                    bf[kh][p] = *(const bf16x8*)&lds[6144 + p * 2048 + n * 16 + (((c ^ sx) & 3) << 2)];
            }
#define DO_PROD(pa, pb)                                                        \
    _Pragma("unroll")                                                          \
    for (int at = 0; at < 2; at++)                                             \
        _Pragma("unroll")                                                      \
        for (int kh = 0; kh < 2; kh++)                                         \
            acc[at][bt] = __builtin_amdgcn_mfma_f32_32x32x16_bf16(             \
                af[at][kh][pa], bf[kh][pb], acc[at][bt], 0, 0, 0);
            DO_PROD(0, 0) DO_PROD(0, 1) DO_PROD(1, 0) DO_PROD(1, 1)
            DO_PROD(0, 2) DO_PROD(2, 0)
#undef DO_PROD
        }
    }

#pragma unroll
    for (int at = 0; at < 2; at++)
#pragma unroll
        for (int bt = 0; bt < 2; bt++) {
            const long gc = colBase + wn + bt * 32 + l31;
#pragma unroll
            for (int r = 0; r < 16; r++) {
                const long gr = rowBase + wm + at * 32 + (r & 3) + 8 * (r >> 2) + 4 * lg;
                const long idx = gr * (long)N + gc;
                float vx = alpha * act_fn<ACT>(acc[at][bt][r]);
                if (HAS_GATE) vx *= Gate[idx];
                if (WRITE_C) {
                    if (beta != 0.0f) vx += beta * C[idx];
                    C[idx] = vx;
                }
                if (WRITE_PLANES) {
                    u32 hh, mm, ll; split3(vx, hh, mm, ll);
                    Pout[idx] = (u16)hh;
                    Pout[sPout + idx] = (u16)mm;
                    Pout[2 * sPout + idx] = (u16)ll;
                }
            }
        }
}

// ---------------------------------------------------------------------------
// RMS norm + exact split to 3 bf16 planes. One block (128 thr × float4) / row.
// ---------------------------------------------------------------------------
__launch_bounds__(128)
__global__ void rms_split_kernel(const float* __restrict__ X, u16* __restrict__ P, long sP) {
    const long row = blockIdx.x;
    const float4 v = *(const float4*)&X[row * D_ + threadIdx.x * 4];
    float ss = v.x * v.x + v.y * v.y + v.z * v.z + v.w * v.w;
#pragma unroll
    for (int off = 32; off > 0; off >>= 1) ss += __shfl_down(ss, off, 64);
    __shared__ float s2[2];
    if ((threadIdx.x & 63) == 0) s2[threadIdx.x >> 6] = ss;
    __syncthreads();
    const float sc = rsqrtf((s2[0] + s2[1]) * (1.0f / (float)D_) + EPS_);
    float o[4] = {v.x * sc, v.y * sc, v.z * sc, v.w * sc};
    u32 h[4], m[4], l[4];
#pragma unroll
    for (int j = 0; j < 4; j++) split3(o[j], h[j], m[j], l[j]);
    const long base = row * D_ + threadIdx.x * 4;
    uint2 ph, pm, pl;
    ph.x = h[0] | (h[1] << 16); ph.y = h[2] | (h[3] << 16);
    pm.x = m[0] | (m[1] << 16); pm.y = m[2] | (m[3] << 16);
    pl.x = l[0] | (l[1] << 16); pl.y = l[2] | (l[3] << 16);
    *(uint2*)&P[base] = ph;
    *(uint2*)&P[sP + base] = pm;
    *(uint2*)&P[2 * sP + base] = pl;
}

// ---------------------------------------------------------------------------
// Weight split + transpose: W [K][N] fp32 -> planes [N][K] bf16 ×3. One-time.
// ---------------------------------------------------------------------------
__launch_bounds__(256)
__global__ void wsplit_kernel(const float* __restrict__ W, u16* __restrict__ P, int K, int N) {
    const int n  = blockIdx.y * 256 + threadIdx.x;
    const int k0 = blockIdx.x * 4;
    const long sP = (long)K * N;
    u32 h[4], m[4], l[4];
#pragma unroll
    for (int j = 0; j < 4; j++) split3(W[(long)(k0 + j) * N + n], h[j], m[j], l[j]);
    const long base = (long)n * K + k0;
    uint2 ph, pm, pl;
    ph.x = h[0] | (h[1] << 16); ph.y = h[2] | (h[3] << 16);
    pm.x = m[0] | (m[1] << 16); pm.y = m[2] | (m[3] << 16);
    pl.x = l[0] | (l[1] << 16); pl.y = l[2] | (l[3] << 16);
    *(uint2*)&P[base] = ph;
    *(uint2*)&P[sP + base] = pm;
    *(uint2*)&P[2 * sP + base] = pl;
}

__launch_bounds__(128)
__global__ void embed_kernel(const int* __restrict__ inputs, const float* __restrict__ emb,
                             float* __restrict__ state) {
    const int row = blockIdx.x;
    const int s  = row & (S_ - 1);
    const int vb = row >> 11;
    const int b  = vb & (B_ - 1);
    const int v  = vb >> 3;
    const int tok = inputs[b * S_ + s];
    const float4 val = *(const float4*)&emb[((long)v * VOCAB_ + tok) * D_ + threadIdx.x * 4];
    *(float4*)&state[(long)row * D_ + threadIdx.x * 4] = val;
}

__launch_bounds__(256)
__global__ void combine_kernel(const float* __restrict__ state, float* __restrict__ comb) {
    const long i = (long)blockIdx.x * 256 + threadIdx.x;
    const float4 a = ((const float4*)state)[i];
    const float4 c = ((const float4*)(state + (long)B_ * S_ * D_))[i];
    float4 o;
    o.x = 0.5f * (a.x + c.x); o.y = 0.5f * (a.y + c.y);
    o.z = 0.5f * (a.z + c.z); o.w = 0.5f * (a.w + c.w);
    ((float4*)comb)[i] = o;
}

extern "C" void kernel_launch(void* const* d_in, const int* in_sizes, int n_in,
                              void* d_out, int out_size, void* d_ws, size_t ws_size,
                              hipStream_t stream) {
    const int*   inputs = (const int*)d_in[0];
    const float* emb = (const float*)d_in[1];
    const float* Wg  = (const float*)d_in[2];
    const float* Wu  = (const float*)d_in[3];
    const float* Wd  = (const float*)d_in[4];
    const float* Wq  = (const float*)d_in[5];
    const float* Wk  = (const float*)d_in[6];
    const float* Wv  = (const float*)d_in[7];
    const float* Wv_o = (const float*)d_in[8];
    const float* Wlm = (const float*)d_in[9];
    float* out = (float*)d_out;

    float* ws    = (float*)d_ws;
    float* state = ws;                         // [0, RD_)
    float* gbuf  = ws + RD_;                   // [RD_, 2RD_)
    float* shr   = ws + 2 * RD_;               // shared region [2RD_, 5RD_)
    float* qbuf  = shr;                        // fp32, live after Wd
    float* kbuf  = shr + RD_;
    float* vbuf  = shr + 2 * RD_;
    u16*   upl   = (u16*)shr;                  // u planes (3 × 2RD_ u16), live Wu→Wd
    u16*   cpl   = (u16*)shr;                  // comb planes (final)
    u16*   npl   = (u16*)(ws + 5 * RD_);       // n/mix planes (3 × RD_ u16) = 1.5RD_ f
    float* accb  = ws + 5 * RD_ + (3 * RD_) / 2;
    u16*   wpl   = (u16*)(accb + (long)VB_ * D_ * D_);
    u16* wgT  = wpl;
    u16* wuT  = wgT + 3L * D_ * D_;
    u16* wdT  = wuT + 3L * D_ * 2 * D_;
    u16* wqT  = wdT + 3L * 2 * D_ * D_;
    u16* wkT  = wqT + 3L * D_ * D_;
    u16* wvT  = wkT + 3L * D_ * D_;
    u16* woT  = wvT + 3L * D_ * D_;
    u16* wlmT = woT + 3L * D_ * D_;

    const float inv_s  = 1.0f / (float)S_;
    const float inv_sd = 0.044194173824159216f;  // 1/sqrt(512)

    hipMemsetAsync(accb, 0, (size_t)VB_ * D_ * D_ * sizeof(float), stream);
    embed_kernel<<<R_, 128, 0, stream>>>(inputs, emb, state);
    // one-time weight split+transpose (bf16 planes [N][K] ×3)
    wsplit_kernel<<<dim3(D_ / 4, D_ / 256), 256, 0, stream>>>(Wg, wgT, D_, D_);
    wsplit_kernel<<<dim3(D_ / 4, 2 * D_ / 256), 256, 0, stream>>>(Wu, wuT, D_, 2 * D_);
    wsplit_kernel<<<dim3(2 * D_ / 4, D_ / 256), 256, 0, stream>>>(Wd, wdT, 2 * D_, D_);
    wsplit_kernel<<<dim3(D_ / 4, D_ / 256), 256, 0, stream>>>(Wq, wqT, D_, D_);
    wsplit_kernel<<<dim3(D_ / 4, D_ / 256), 256, 0, stream>>>(Wk, wkT, D_, D_);
    wsplit_kernel<<<dim3(D_ / 4, D_ / 256), 256, 0, stream>>>(Wv, wvT, D_, D_);
    wsplit_kernel<<<dim3(D_ / 4, D_ / 256), 256, 0, stream>>>(Wv_o, woT, D_, D_);
    wsplit_kernel<<<dim3(D_ / 4, VOCAB_ / 256), 256, 0, stream>>>(Wlm, wlmT, D_, VOCAB_);

    for (int step = 0; step < STEPS_; step++) {
        rms_split_kernel<<<R_, 128, 0, stream>>>(state, npl, RD_);
        gemm_pl<ACT_SIGMOID, false, true, false><<<dim3(4, 256), 256, 0, stream>>>(
            npl, wgT, gbuf, nullptr, nullptr, R_, D_, D_, RD_, (long)D_ * D_, 0, 1.0f, 0.0f);
        gemm_pl<ACT_GELU, false, false, true><<<dim3(8, 256), 256, 0, stream>>>(
            npl, wuT, nullptr, nullptr, upl, R_, 2 * D_, D_, RD_, (long)D_ * 2 * D_, 2 * RD_, 1.0f, 0.0f);
        gemm_pl<ACT_IDENT, true, true, false><<<dim3(4, 256), 256, 0, stream>>>(
            upl, wdT, state, gbuf, nullptr, R_, D_, 2 * D_, 2 * RD_, (long)2 * D_ * D_, 0, 1.0f, 1.0f);
        rms_split_kernel<<<R_, 128, 0, stream>>>(state, npl, RD_);
        gemm_pl<ACT_PHI, false, true, false><<<dim3(4, 256), 256, 0, stream>>>(
            npl, wqT, qbuf, nullptr, nullptr, R_, D_, D_, RD_, (long)D_ * D_, 0, 1.0f, 0.0f);
        gemm_pl<ACT_PHI, false, true, false><<<dim3(4, 256), 256, 0, stream>>>(
            npl, wkT, kbuf, nullptr, nullptr, R_, D_, D_, RD_, (long)D_ * D_, 0, 1.0f, 0.0f);
        gemm_pl<ACT_IDENT, false, true, false><<<dim3(4, 256), 256, 0, stream>>>(
            npl, wvT, vbuf, nullptr, nullptr, R_, D_, D_, RD_, (long)D_ * D_, 0, 1.0f, 0.0f);
        // acc = DECAY*acc + (k^T v)*inv_s
        gemm_mfma<ACT_IDENT, false, true, true, false><<<dim3(4, 4, VB_), 256, 0, stream>>>(
            kbuf, vbuf, accb, nullptr, nullptr, D_, D_, S_,
            (long)S_ * D_, (long)S_ * D_, (long)D_ * D_, 0, inv_s, DECAY_);
        // mixed = (q @ acc) * inv_sqrt_d  → split planes (reuse npl)
        gemm_mfma<ACT_IDENT, false, false, false, true><<<dim3(4, 16, VB_), 256, 0, stream>>>(
            qbuf, accb, nullptr, nullptr, npl, S_, D_, D_,
            (long)S_ * D_, (long)D_ * D_, (long)S_ * D_, RD_, inv_sd, 0.0f);
        // state += mixed @ Wo
        gemm_pl<ACT_IDENT, false, true, false><<<dim3(4, 256), 256, 0, stream>>>(
            npl, woT, state, nullptr, nullptr, R_, D_, D_, RD_, (long)D_ * D_, 0, 1.0f, 1.0f);
    }

    combine_kernel<<<(B_ * S_ * D_ / 4) / 256, 256, 0, stream>>>(state, gbuf);
    rms_split_kernel<<<B_ * S_, 128, 0, stream>>>(gbuf, cpl, (long)B_ * S_ * D_);
    gemm_pl<ACT_IDENT, false, true, false><<<dim3(64, 128), 256, 0, stream>>>(
        cpl, wlmT, out, nullptr, nullptr, B_ * S_, VOCAB_, D_,
        (long)B_ * S_ * D_, (long)VOCAB_ * D_, 0, 1.0f, 0.0f);
}